// Round 4
// baseline (689.442 us; speedup 1.0000x reference)
//
#include <hip/hip_runtime.h>

// ---------------- problem constants ----------------
#define HH 16
#define DD 64
#define SQ 1024          // queries
#define LW 8192          // attention window (keys)
#define OLDK 7168        // old (already-RoPE'd) keys in window
#define CACHE_BASE 2560  // cache row index of window position 0
#define SFRAME 9728      // START_FRAME
#define KSPLIT 16
#define KPER (LW / KSPLIT)   // 512 keys per split
#define NSTEP (KPER / 64)    // 8 K-steps of 64 keys

// ws layout (bytes)
#define KB_OFF 0u                    // bf16 Kb[h][8192][64]    = 16 MiB
#define VT_OFF 16777216u             // bf16 Vt[h][64][8192]    = 16 MiB
#define QB_OFF 33554432u             // bf16 Qb[h][1024][64]    =  2 MiB
#define OP_OFF 35651584u             // bf16 Op[ks][h][1024][64]= 32 MiB
#define LP_OFF 69206016u             // f32  Lp[ks][h][1024]    =  1 MiB
// total ~67 MiB of ws

typedef __bf16 bf16x8 __attribute__((ext_vector_type(8)));
typedef float floatx16 __attribute__((ext_vector_type(16)));
typedef unsigned uintx2 __attribute__((ext_vector_type(2)));
typedef unsigned uintx4 __attribute__((ext_vector_type(4)));

__device__ __forceinline__ unsigned short f2bf(float f) {
  unsigned u = __builtin_bit_cast(unsigned, f);
  u += 0x7fffu + ((u >> 16) & 1u);           // RNE
  return (unsigned short)(u >> 16);
}

__device__ __forceinline__ float fast_exp2(float x) {
#if __has_builtin(__builtin_amdgcn_exp2f)
  return __builtin_amdgcn_exp2f(x);
#else
  return __builtin_exp2f(x);
#endif
}

// pack two f32 -> bf16x2 (as uint). element0 = a (low 16), element1 = b.
__device__ __forceinline__ unsigned pack_bf2(float a, float b) {
#if __has_builtin(__builtin_amdgcn_cvt_pk_bf16_f32)
  typedef __bf16 bf16x2_t __attribute__((ext_vector_type(2)));
  bf16x2_t r = __builtin_amdgcn_cvt_pk_bf16_f32(a, b);
  return __builtin_bit_cast(unsigned, r);
#else
  unsigned ua = __builtin_bit_cast(unsigned, a) + 0x8000u;  // round-half-up
  unsigned ub = __builtin_bit_cast(unsigned, b) + 0x8000u;
  return __builtin_amdgcn_perm(ub, ua, 0x07060302);         // [ua.hi16 | ub.hi16]
#endif
}

__device__ __forceinline__ void async16(void* lds, const void* g) {
  __builtin_amdgcn_global_load_lds((__attribute__((address_space(1))) void*)(g),
                                   (__attribute__((address_space(3))) void*)(lds),
                                   16, 0, 0);
}

// ---------------- prepass: build bf16 Kb / Vt(transposed) / Qb(rope*scale) ----
__global__ __launch_bounds__(256) void prepass(
    const float* __restrict__ qin, const float* __restrict__ kin,
    const float* __restrict__ vin, const float* __restrict__ ck,
    const float* __restrict__ cv, const float* __restrict__ fc,
    const float* __restrict__ fs, unsigned short* __restrict__ Kb,
    unsigned short* __restrict__ Vt, unsigned short* __restrict__ Qb) {
  int b = blockIdx.x, t = threadIdx.x;
  if (b < 1024) {
    // V transpose: 128kk x 64d fp32 tile (XOR col-group swizzle) -> Vt[h][d][kk]
    __shared__ float tl[128 * 64];  // row kk; float4 group c stored at cg = c ^ (kk>>3)
    int h = b >> 6, kk0 = (b & 63) * 128;
    int c = t & 15;
#pragma unroll
    for (int it = 0; it < 8; it++) {
      int kk = it * 16 + (t >> 4);
      int gk = kk0 + kk;
      const float* src = (gk < OLDK)
                             ? cv + (CACHE_BASE + gk) * (HH * DD) + h * DD + 4 * c
                             : vin + (gk - OLDK) * (HH * DD) + h * DD + 4 * c;
      float4 vv = *(const float4*)src;
      int cg = c ^ (kk >> 3);
      *(float4*)(tl + kk * 64 + cg * 4) = vv;
    }
    __syncthreads();
    int kq = t & 15;
#pragma unroll
    for (int jt = 0; jt < 4; jt++) {
      int d = jt * 16 + (t >> 4);
      ushort4 lo, hi;
      unsigned short tmp[8];
#pragma unroll
      for (int j = 0; j < 8; j++) {
        int kk = 8 * kq + j;
        int cg = (d >> 2) ^ kq;
        tmp[j] = f2bf(tl[kk * 64 + cg * 4 + (d & 3)]);
      }
      lo.x = tmp[0]; lo.y = tmp[1]; lo.z = tmp[2]; lo.w = tmp[3];
      hi.x = tmp[4]; hi.y = tmp[5]; hi.z = tmp[6]; hi.w = tmp[7];
      unsigned short* dst = Vt + (h * DD + d) * LW + kk0 + 8 * kq;
      *(ushort4*)(dst) = lo;
      *(ushort4*)(dst + 4) = hi;
    }
  } else if (b < 8192) {
    // K copy (old keys, already RoPE'd in cache): [kk][h][d] -> Kb[h][kk][d]
    int b1 = b - 1024;
    int h = b1 / 448, g = b1 % 448;
    int kk = g * 16 + (t >> 4);
    int lane = t & 15;
    float4 val = *(const float4*)(ck + (CACHE_BASE + kk) * (HH * DD) + h * DD + lane * 4);
    ushort4 o;
    o.x = f2bf(val.x); o.y = f2bf(val.y); o.z = f2bf(val.z); o.w = f2bf(val.w);
    *(ushort4*)(Kb + (h * LW + kk) * DD + lane * 4) = o;
  } else if (b < 10240) {
    // K rope (new keys)
    int b2 = b - 8192;
    int rh = b2 * 8 + (t >> 5);
    int s = rh >> 4, h = rh & 15, i = t & 31;
    float2 x = *(const float2*)(kin + s * (HH * DD) + h * DD + 2 * i);
    float c = fc[(SFRAME + s) * DD + 2 * i];
    float sn = fs[(SFRAME + s) * DD + 2 * i];
    ushort2 o;
    o.x = f2bf(x.x * c - x.y * sn);
    o.y = f2bf(x.y * c + x.x * sn);
    *(ushort2*)(Kb + (h * LW + OLDK + s) * DD + 2 * i) = o;
  } else {
    // Q rope + fold (1/sqrt(D)) * log2(e) so scores feed exp2 directly
    int b3 = b - 10240;
    int rh = b3 * 8 + (t >> 5);
    int s = rh >> 4, h = rh & 15, i = t & 31;
    const float SC = 0.18033688011112042f;  // 0.125 * log2(e)
    float2 x = *(const float2*)(qin + s * (HH * DD) + h * DD + 2 * i);
    float c = fc[(SFRAME + s) * DD + 2 * i];
    float sn = fs[(SFRAME + s) * DD + 2 * i];
    ushort2 o;
    o.x = f2bf((x.x * c - x.y * sn) * SC);
    o.y = f2bf((x.y * c + x.x * sn) * SC);
    *(ushort2*)(Qb + (h * SQ + s) * DD + 2 * i) = o;
  }
}

// ---------------- flash attention (no-max exp2 softmax, K-split 16) ----------
// 4 blocks/CU (4 independent barrier domains) for cross-block phase overlap:
// MFMA-phase of one block hides exp2/pack VALU-phase of another.
__global__ __launch_bounds__(256, 4) void attn(
    const unsigned short* __restrict__ Kb, const unsigned short* __restrict__ Vt,
    const unsigned short* __restrict__ Qb, unsigned short* __restrict__ Op,
    float* __restrict__ Lp) {
  __shared__ __align__(16) unsigned char sK[2][8192];  // 64kk x 64d bf16, swizzled granules
  __shared__ __align__(16) unsigned char sV[2][8192];  // 64d x 64kk bf16, swizzled granules

  int bid = blockIdx.x;
  int g = bid & 255, qb = bid >> 8;
  int h = g & 15, ks = g >> 4;
  int t = threadIdx.x;
  int w = t >> 6, lane = t & 63;
  int l31 = lane & 31, e = lane >> 5;
  int q0 = qb * 256 + w * 64;

  // granule-position bases for the XOR swizzle (rows l31 and l31+32)
  int baseA = (l31 & 7) ^ ((l31 >> 3) & 7);
  int baseB = (l31 & 7) ^ (((l31 >> 3) + 4) & 7);

  // hoisted Q B-fragments, 2 q-tiles x 4 d-slices: B[k=d][n=q], n=l31, k=16c+8e+j
  bf16x8 qf[2][4];
#pragma unroll
  for (int tq = 0; tq < 2; tq++) {
    const unsigned short* qptr = Qb + (h * SQ + q0 + 32 * tq + l31) * DD + 8 * e;
#pragma unroll
    for (int c = 0; c < 4; c++) qf[tq][c] = *(const bf16x8*)(qptr + 16 * c);
  }

  floatx16 o[2][2];   // [tq][d-half], O^T[d][q]
#pragma unroll
  for (int a = 0; a < 2; a++)
#pragma unroll
    for (int bb = 0; bb < 2; bb++)
#pragma unroll
      for (int i = 0; i < 16; i++) o[a][bb][i] = 0.f;
  float ls[2] = {0.f, 0.f};

  const unsigned short* KbH = Kb + h * (LW * DD);
  const unsigned short* VtH = Vt + h * (DD * LW);
  int kkBase = ks * KPER;

  // stage one 64kk tile into buffer `buf` (4 async16 per wave)
  auto stage = [&](int buf, int kk0) {
#pragma unroll
    for (int hf = 0; hf < 2; hf++) {
      int gi = w * 128 + hf * 64 + lane;
      int rr = gi >> 3;                                  // kk for K, d for V
      int src = (gi & 7) ^ (rr & 7) ^ ((rr >> 3) & 7);   // source granule at position gi&7
      async16(sK[buf] + gi * 16, KbH + (kk0 + rr) * DD + src * 8);
      async16(sV[buf] + gi * 16, VtH + rr * LW + kk0 + src * 8);
    }
  };

  stage(0, kkBase);

  for (int st = 0; st < NSTEP; st++) {
    __syncthreads();                       // buf[st&1] ready; buf[(st+1)&1] free
    if (st + 1 < NSTEP) stage((st + 1) & 1, kkBase + (st + 1) * 64);
    const unsigned char* cK = sK[st & 1];
    const unsigned char* cV = sV[st & 1];

    // S^T[kk][q] = K . Q^T  (scores pre-scaled by 0.125*log2e via Qb)
    floatx16 s[2][2];   // [tq][kk-half]
#pragma unroll
    for (int a = 0; a < 2; a++)
#pragma unroll
      for (int bb = 0; bb < 2; bb++)
#pragma unroll
        for (int i = 0; i < 16; i++) s[a][bb][i] = 0.f;
#pragma unroll
    for (int c = 0; c < 4; c++) {
      int pA = (2 * c + e) ^ baseA;
      int pB = (2 * c + e) ^ baseB;
      bf16x8 ka = *(const bf16x8*)(cK + (l31 * 8 + pA) * 16);
      bf16x8 kb = *(const bf16x8*)(cK + ((l31 + 32) * 8 + pB) * 16);
      s[0][0] = __builtin_amdgcn_mfma_f32_32x32x16_bf16(ka, qf[0][c], s[0][0], 0, 0, 0);
      s[0][1] = __builtin_amdgcn_mfma_f32_32x32x16_bf16(kb, qf[0][c], s[0][1], 0, 0, 0);
      s[1][0] = __builtin_amdgcn_mfma_f32_32x32x16_bf16(ka, qf[1][c], s[1][0], 0, 0, 0);
      s[1][1] = __builtin_amdgcn_mfma_f32_32x32x16_bf16(kb, qf[1][c], s[1][1], 0, 0, 0);
    }

    // P = exp2(S'); row-sums; pack to bf16x2 in C-layout register blocks
    unsigned pk[2][2][4][2];   // [tq][tk][block b][pair p]
#pragma unroll
    for (int tq = 0; tq < 2; tq++) {
#pragma unroll
      for (int tk = 0; tk < 2; tk++) {
#pragma unroll
        for (int i = 0; i < 16; i++) s[tq][tk][i] = fast_exp2(s[tq][tk][i]);
        float ps = 0.f;
#pragma unroll
        for (int i = 0; i < 16; i++) ps += s[tq][tk][i];
        ls[tq] += ps;
#pragma unroll
        for (int bq = 0; bq < 4; bq++)
#pragma unroll
          for (int p = 0; p < 2; p++)
            pk[tq][tk][bq][p] = pack_bf2(s[tq][tk][4 * bq + 2 * p], s[tq][tk][4 * bq + 2 * p + 1]);
      }
    }

    // C-layout -> B-operand layout via cross-half register swap
    bf16x8 pf[2][4];   // [tq][kc_global]
#pragma unroll
    for (int tq = 0; tq < 2; tq++) {
#pragma unroll
      for (int tk = 0; tk < 2; tk++) {
#pragma unroll
        for (int kcp = 0; kcp < 2; kcp++) {
          uintx2 r0 = __builtin_amdgcn_permlane32_swap(pk[tq][tk][2 * kcp][0],
                                                       pk[tq][tk][2 * kcp + 1][0], false, false);
          uintx2 r1 = __builtin_amdgcn_permlane32_swap(pk[tq][tk][2 * kcp][1],
                                                       pk[tq][tk][2 * kcp + 1][1], false, false);
          uintx4 f;
          f[0] = r0[0]; f[1] = r1[0]; f[2] = r0[1]; f[3] = r1[1];
          pf[tq][2 * tk + kcp] = __builtin_bit_cast(bf16x8, f);
        }
      }
    }

    // O^T[d][q] += V^T . P^T
#pragma unroll
    for (int kc = 0; kc < 4; kc++) {
      int pA = (2 * kc + e) ^ baseA;
      int pB = (2 * kc + e) ^ baseB;
      bf16x8 va = *(const bf16x8*)(cV + (l31 * 8 + pA) * 16);
      bf16x8 vb = *(const bf16x8*)(cV + ((l31 + 32) * 8 + pB) * 16);
      o[0][0] = __builtin_amdgcn_mfma_f32_32x32x16_bf16(va, pf[0][kc], o[0][0], 0, 0, 0);
      o[0][1] = __builtin_amdgcn_mfma_f32_32x32x16_bf16(vb, pf[0][kc], o[0][1], 0, 0, 0);
      o[1][0] = __builtin_amdgcn_mfma_f32_32x32x16_bf16(va, pf[1][kc], o[1][0], 0, 0, 0);
      o[1][1] = __builtin_amdgcn_mfma_f32_32x32x16_bf16(vb, pf[1][kc], o[1][1], 0, 0, 0);
    }
  }

  // epilogue: store split numerators (bf16) + denominators (f32)
#pragma unroll
  for (int tq = 0; tq < 2; tq++) {
    float l = ls[tq];
    l += __shfl_xor(l, 32, 64);
    int qrow = q0 + 32 * tq + l31;
    unsigned short* op = Op + (((ks * 16 + h) * SQ) + qrow) * DD;
#pragma unroll
    for (int t4 = 0; t4 < 4; t4++) {
      uint2 a, b;
      a.x = pack_bf2(o[tq][0][4 * t4 + 0], o[tq][0][4 * t4 + 1]);
      a.y = pack_bf2(o[tq][0][4 * t4 + 2], o[tq][0][4 * t4 + 3]);
      b.x = pack_bf2(o[tq][1][4 * t4 + 0], o[tq][1][4 * t4 + 1]);
      b.y = pack_bf2(o[tq][1][4 * t4 + 2], o[tq][1][4 * t4 + 3]);
      *(uint2*)(op + 8 * t4 + 4 * e) = a;         // d = 8t4+4e+0..3
      *(uint2*)(op + 32 + 8 * t4 + 4 * e) = b;    // d = 32+8t4+4e+0..3
    }
    if (e == 0) Lp[(ks * 16 + h) * SQ + qrow] = l;
  }
}

// ---------------- combine splits (bf16 numerators, 4 d per thread) -----------
__global__ __launch_bounds__(256) void combine(const unsigned short* __restrict__ Op,
                                               const float* __restrict__ Lp,
                                               float* __restrict__ out) {
  int idx = blockIdx.x * 256 + threadIdx.x;     // 262144 threads
  int d4 = idx & 15, q = (idx >> 4) & 1023, h = idx >> 14;
  float num[4] = {0.f, 0.f, 0.f, 0.f};
  float den = 0.f;
#pragma unroll
  for (int s = 0; s < KSPLIT; s++) {
    int row = (s * 16 + h) * SQ + q;
    uint2 pkv = *(const uint2*)(Op + row * DD + 4 * d4);
    num[0] += __builtin_bit_cast(float, pkv.x << 16);
    num[1] += __builtin_bit_cast(float, pkv.x & 0xffff0000u);
    num[2] += __builtin_bit_cast(float, pkv.y << 16);
    num[3] += __builtin_bit_cast(float, pkv.y & 0xffff0000u);
    den += Lp[row];
  }
  float r = 1.0f / den;
  float4 ov;
  ov.x = num[0] * r; ov.y = num[1] * r; ov.z = num[2] * r; ov.w = num[3] * r;
  *(float4*)(out + q * (HH * DD) + h * DD + 4 * d4) = ov;
}

extern "C" void kernel_launch(void* const* d_in, const int* in_sizes, int n_in,
                              void* d_out, int out_size, void* d_ws, size_t ws_size,
                              hipStream_t stream) {
  const float* q  = (const float*)d_in[0];
  const float* k  = (const float*)d_in[1];
  const float* v  = (const float*)d_in[2];
  const float* ck = (const float*)d_in[3];
  const float* cv = (const float*)d_in[4];
  const float* fc = (const float*)d_in[5];
  const float* fs = (const float*)d_in[6];
  float* out = (float*)d_out;
  char* ws = (char*)d_ws;

  unsigned short* Kb = (unsigned short*)(ws + KB_OFF);
  unsigned short* Vt = (unsigned short*)(ws + VT_OFF);
  unsigned short* Qb = (unsigned short*)(ws + QB_OFF);
  unsigned short* Op = (unsigned short*)(ws + OP_OFF);
  float* Lp = (float*)(ws + LP_OFF);

  prepass<<<12288, 256, 0, stream>>>(q, k, v, ck, cv, fc, fs, Kb, Vt, Qb);
  attn<<<1024, 256, 0, stream>>>(Kb, Vt, Qb, Op, Lp);
  combine<<<1024, 256, 0, stream>>>(Op, Lp, out);
}

// Round 5
// 273.833 us; speedup vs baseline: 2.5177x; 2.5177x over previous
//
#include <hip/hip_runtime.h>

// ---------------- problem constants ----------------
#define HH 16
#define DD 64
#define SQ 1024          // queries
#define LW 8192          // attention window (keys)
#define OLDK 7168        // old (already-RoPE'd) keys in window
#define CACHE_BASE 2560  // cache row index of window position 0
#define SFRAME 9728      // START_FRAME
#define KSPLIT 16
#define KPER (LW / KSPLIT)   // 512 keys per split
#define NSTEP (KPER / 64)    // 8 K-steps of 64 keys

// ws layout (bytes)
#define KB_OFF 0u                    // bf16 Kb[h][8192][64]    = 16 MiB
#define VT_OFF 16777216u             // bf16 Vt[h][64][8192]    = 16 MiB
#define QB_OFF 33554432u             // bf16 Qb[h][1024][64]    =  2 MiB
#define OP_OFF 35651584u             // bf16 Op[ks][h][1024][64]= 32 MiB
#define LP_OFF 69206016u             // f32  Lp[ks][h][1024]    =  1 MiB
// total ~67 MiB of ws

typedef __bf16 bf16x8 __attribute__((ext_vector_type(8)));
typedef float floatx16 __attribute__((ext_vector_type(16)));
typedef unsigned uintx2 __attribute__((ext_vector_type(2)));
typedef unsigned uintx4 __attribute__((ext_vector_type(4)));

__device__ __forceinline__ unsigned short f2bf(float f) {
  unsigned u = __builtin_bit_cast(unsigned, f);
  u += 0x7fffu + ((u >> 16) & 1u);           // RNE
  return (unsigned short)(u >> 16);
}

__device__ __forceinline__ float fast_exp2(float x) {
#if __has_builtin(__builtin_amdgcn_exp2f)
  return __builtin_amdgcn_exp2f(x);
#else
  return __builtin_exp2f(x);
#endif
}

// pack two f32 -> bf16x2 (as uint). element0 = a (low 16), element1 = b.
__device__ __forceinline__ unsigned pack_bf2(float a, float b) {
#if __has_builtin(__builtin_amdgcn_cvt_pk_bf16_f32)
  typedef __bf16 bf16x2_t __attribute__((ext_vector_type(2)));
  bf16x2_t r = __builtin_amdgcn_cvt_pk_bf16_f32(a, b);
  return __builtin_bit_cast(unsigned, r);
#else
  unsigned ua = __builtin_bit_cast(unsigned, a) + 0x8000u;  // round-half-up
  unsigned ub = __builtin_bit_cast(unsigned, b) + 0x8000u;
  return __builtin_amdgcn_perm(ub, ua, 0x07060302);         // [ua.hi16 | ub.hi16]
#endif
}

__device__ __forceinline__ void async16(void* lds, const void* g) {
  __builtin_amdgcn_global_load_lds((__attribute__((address_space(1))) void*)(g),
                                   (__attribute__((address_space(3))) void*)(lds),
                                   16, 0, 0);
}

// ---------------- prepass: build bf16 Kb / Vt(transposed) / Qb(rope*scale) ----
__global__ __launch_bounds__(256) void prepass(
    const float* __restrict__ qin, const float* __restrict__ kin,
    const float* __restrict__ vin, const float* __restrict__ ck,
    const float* __restrict__ cv, const float* __restrict__ fc,
    const float* __restrict__ fs, unsigned short* __restrict__ Kb,
    unsigned short* __restrict__ Vt, unsigned short* __restrict__ Qb) {
  int b = blockIdx.x, t = threadIdx.x;
  if (b < 1024) {
    // V transpose: 128kk x 64d fp32 tile (XOR col-group swizzle) -> Vt[h][d][kk]
    __shared__ float tl[128 * 64];  // row kk; float4 group c stored at cg = c ^ (kk>>3)
    int h = b >> 6, kk0 = (b & 63) * 128;
    int c = t & 15;
#pragma unroll
    for (int it = 0; it < 8; it++) {
      int kk = it * 16 + (t >> 4);
      int gk = kk0 + kk;
      const float* src = (gk < OLDK)
                             ? cv + (CACHE_BASE + gk) * (HH * DD) + h * DD + 4 * c
                             : vin + (gk - OLDK) * (HH * DD) + h * DD + 4 * c;
      float4 vv = *(const float4*)src;
      int cg = c ^ (kk >> 3);
      *(float4*)(tl + kk * 64 + cg * 4) = vv;
    }
    __syncthreads();
    int kq = t & 15;
#pragma unroll
    for (int jt = 0; jt < 4; jt++) {
      int d = jt * 16 + (t >> 4);
      ushort4 lo, hi;
      unsigned short tmp[8];
#pragma unroll
      for (int j = 0; j < 8; j++) {
        int kk = 8 * kq + j;
        int cg = (d >> 2) ^ kq;
        tmp[j] = f2bf(tl[kk * 64 + cg * 4 + (d & 3)]);
      }
      lo.x = tmp[0]; lo.y = tmp[1]; lo.z = tmp[2]; lo.w = tmp[3];
      hi.x = tmp[4]; hi.y = tmp[5]; hi.z = tmp[6]; hi.w = tmp[7];
      unsigned short* dst = Vt + (h * DD + d) * LW + kk0 + 8 * kq;
      *(ushort4*)(dst) = lo;
      *(ushort4*)(dst + 4) = hi;
    }
  } else if (b < 8192) {
    // K copy (old keys, already RoPE'd in cache): [kk][h][d] -> Kb[h][kk][d]
    int b1 = b - 1024;
    int h = b1 / 448, g = b1 % 448;
    int kk = g * 16 + (t >> 4);
    int lane = t & 15;
    float4 val = *(const float4*)(ck + (CACHE_BASE + kk) * (HH * DD) + h * DD + lane * 4);
    ushort4 o;
    o.x = f2bf(val.x); o.y = f2bf(val.y); o.z = f2bf(val.z); o.w = f2bf(val.w);
    *(ushort4*)(Kb + (h * LW + kk) * DD + lane * 4) = o;
  } else if (b < 10240) {
    // K rope (new keys)
    int b2 = b - 8192;
    int rh = b2 * 8 + (t >> 5);
    int s = rh >> 4, h = rh & 15, i = t & 31;
    float2 x = *(const float2*)(kin + s * (HH * DD) + h * DD + 2 * i);
    float c = fc[(SFRAME + s) * DD + 2 * i];
    float sn = fs[(SFRAME + s) * DD + 2 * i];
    ushort2 o;
    o.x = f2bf(x.x * c - x.y * sn);
    o.y = f2bf(x.y * c + x.x * sn);
    *(ushort2*)(Kb + (h * LW + OLDK + s) * DD + 2 * i) = o;
  } else {
    // Q rope + fold (1/sqrt(D)) * log2(e) so scores feed exp2 directly
    int b3 = b - 10240;
    int rh = b3 * 8 + (t >> 5);
    int s = rh >> 4, h = rh & 15, i = t & 31;
    const float SC = 0.18033688011112042f;  // 0.125 * log2(e)
    float2 x = *(const float2*)(qin + s * (HH * DD) + h * DD + 2 * i);
    float c = fc[(SFRAME + s) * DD + 2 * i];
    float sn = fs[(SFRAME + s) * DD + 2 * i];
    ushort2 o;
    o.x = f2bf((x.x * c - x.y * sn) * SC);
    o.y = f2bf((x.y * c + x.x * sn) * SC);
    *(ushort2*)(Qb + (h * SQ + s) * DD + 2 * i) = o;
  }
}

// ---------------- flash attention (no-max exp2 softmax, K-split 16) ----------
// Target 3 blocks/CU (3 independent barrier domains) for cross-block phase
// overlap. Registers trimmed via tk-split of the S/exp2/pack phase so the
// peak live set fits 512/3 = 170 regs WITHOUT spilling (R4 post-mortem:
// launch_bounds(256,4) forced accumulator spill -> 2.6 GB scratch traffic).
__global__ __launch_bounds__(256, 3) void attn(
    const unsigned short* __restrict__ Kb, const unsigned short* __restrict__ Vt,
    const unsigned short* __restrict__ Qb, unsigned short* __restrict__ Op,
    float* __restrict__ Lp) {
  __shared__ __align__(16) unsigned char sK[2][8192];  // 64kk x 64d bf16, swizzled granules
  __shared__ __align__(16) unsigned char sV[2][8192];  // 64d x 64kk bf16, swizzled granules

  int bid = blockIdx.x;
  int g = bid & 255, qb = bid >> 8;
  int h = g & 15, ks = g >> 4;
  int t = threadIdx.x;
  int w = t >> 6, lane = t & 63;
  int l31 = lane & 31, e = lane >> 5;
  int q0 = qb * 256 + w * 64;

  // granule-position bases for the XOR swizzle (rows l31 and l31+32)
  int baseA = (l31 & 7) ^ ((l31 >> 3) & 7);
  int baseB = (l31 & 7) ^ (((l31 >> 3) + 4) & 7);

  // hoisted Q B-fragments, 2 q-tiles x 4 d-slices: B[k=d][n=q], n=l31, k=16c+8e+j
  bf16x8 qf[2][4];
#pragma unroll
  for (int tq = 0; tq < 2; tq++) {
    const unsigned short* qptr = Qb + (h * SQ + q0 + 32 * tq + l31) * DD + 8 * e;
#pragma unroll
    for (int c = 0; c < 4; c++) qf[tq][c] = *(const bf16x8*)(qptr + 16 * c);
  }

  floatx16 o[2][2];   // [tq][d-half], O^T[d][q]
#pragma unroll
  for (int a = 0; a < 2; a++)
#pragma unroll
    for (int bb = 0; bb < 2; bb++)
#pragma unroll
      for (int i = 0; i < 16; i++) o[a][bb][i] = 0.f;
  float ls[2] = {0.f, 0.f};

  const unsigned short* KbH = Kb + h * (LW * DD);
  const unsigned short* VtH = Vt + h * (DD * LW);
  int kkBase = ks * KPER;

  // stage one 64kk tile into buffer `buf` (4 async16 per wave)
  auto stage = [&](int buf, int kk0) {
#pragma unroll
    for (int hf = 0; hf < 2; hf++) {
      int gi = w * 128 + hf * 64 + lane;
      int rr = gi >> 3;                                  // kk for K, d for V
      int src = (gi & 7) ^ (rr & 7) ^ ((rr >> 3) & 7);   // source granule at position gi&7
      async16(sK[buf] + gi * 16, KbH + (kk0 + rr) * DD + src * 8);
      async16(sV[buf] + gi * 16, VtH + rr * LW + kk0 + src * 8);
    }
  };

  stage(0, kkBase);

  for (int st = 0; st < NSTEP; st++) {
    __syncthreads();                       // buf[st&1] ready; buf[(st+1)&1] free
    if (st + 1 < NSTEP) stage((st + 1) & 1, kkBase + (st + 1) * 64);
    const unsigned char* cK = sK[st & 1];
    const unsigned char* cV = sV[st & 1];

    // S-phase, tk-split to halve transient registers:
    // tk=0 -> kk rows [0,32) (row l31, swizzle baseA); tk=1 -> rows [32,64).
    bf16x8 pf[2][4];   // [tq][kc_global] P in B-operand layout
#pragma unroll
    for (int tk = 0; tk < 2; tk++) {
      int rowOff = (l31 + 32 * tk) * 8;
      int base = tk ? baseB : baseA;
      floatx16 s0, s1;   // [tq], 16 kk-rows of this half
#pragma unroll
      for (int i = 0; i < 16; i++) { s0[i] = 0.f; s1[i] = 0.f; }
#pragma unroll
      for (int c = 0; c < 4; c++) {
        int p = (2 * c + e) ^ base;
        bf16x8 ka = *(const bf16x8*)(cK + (rowOff + p) * 16);
        s0 = __builtin_amdgcn_mfma_f32_32x32x16_bf16(ka, qf[0][c], s0, 0, 0, 0);
        s1 = __builtin_amdgcn_mfma_f32_32x32x16_bf16(ka, qf[1][c], s1, 0, 0, 0);
      }
      // P = exp2(S'); row-sums; pack; C-layout -> B-operand via permlane swap
#pragma unroll
      for (int tq = 0; tq < 2; tq++) {
        floatx16& sv = tq ? s1 : s0;
#pragma unroll
        for (int i = 0; i < 16; i++) sv[i] = fast_exp2(sv[i]);
        float ps = 0.f;
#pragma unroll
        for (int i = 0; i < 16; i++) ps += sv[i];
        ls[tq] += ps;
#pragma unroll
        for (int kcp = 0; kcp < 2; kcp++) {
          unsigned u0 = pack_bf2(sv[8 * kcp + 0], sv[8 * kcp + 1]);
          unsigned u1 = pack_bf2(sv[8 * kcp + 2], sv[8 * kcp + 3]);
          unsigned u2 = pack_bf2(sv[8 * kcp + 4], sv[8 * kcp + 5]);
          unsigned u3 = pack_bf2(sv[8 * kcp + 6], sv[8 * kcp + 7]);
          uintx2 r0 = __builtin_amdgcn_permlane32_swap(u0, u2, false, false);
          uintx2 r1 = __builtin_amdgcn_permlane32_swap(u1, u3, false, false);
          uintx4 f;
          f[0] = r0[0]; f[1] = r1[0]; f[2] = r0[1]; f[3] = r1[1];
          pf[tq][2 * tk + kcp] = __builtin_bit_cast(bf16x8, f);
        }
      }
    }

    // O^T[d][q] += V^T . P^T
#pragma unroll
    for (int kc = 0; kc < 4; kc++) {
      int pA = (2 * kc + e) ^ baseA;
      int pB = (2 * kc + e) ^ baseB;
      bf16x8 va = *(const bf16x8*)(cV + (l31 * 8 + pA) * 16);
      bf16x8 vb = *(const bf16x8*)(cV + ((l31 + 32) * 8 + pB) * 16);
      o[0][0] = __builtin_amdgcn_mfma_f32_32x32x16_bf16(va, pf[0][kc], o[0][0], 0, 0, 0);
      o[0][1] = __builtin_amdgcn_mfma_f32_32x32x16_bf16(vb, pf[0][kc], o[0][1], 0, 0, 0);
      o[1][0] = __builtin_amdgcn_mfma_f32_32x32x16_bf16(va, pf[1][kc], o[1][0], 0, 0, 0);
      o[1][1] = __builtin_amdgcn_mfma_f32_32x32x16_bf16(vb, pf[1][kc], o[1][1], 0, 0, 0);
    }
  }

  // epilogue: store split numerators (bf16) + denominators (f32)
#pragma unroll
  for (int tq = 0; tq < 2; tq++) {
    float l = ls[tq];
    l += __shfl_xor(l, 32, 64);
    int qrow = q0 + 32 * tq + l31;
    unsigned short* op = Op + (((ks * 16 + h) * SQ) + qrow) * DD;
#pragma unroll
    for (int t4 = 0; t4 < 4; t4++) {
      uint2 a, b;
      a.x = pack_bf2(o[tq][0][4 * t4 + 0], o[tq][0][4 * t4 + 1]);
      a.y = pack_bf2(o[tq][0][4 * t4 + 2], o[tq][0][4 * t4 + 3]);
      b.x = pack_bf2(o[tq][1][4 * t4 + 0], o[tq][1][4 * t4 + 1]);
      b.y = pack_bf2(o[tq][1][4 * t4 + 2], o[tq][1][4 * t4 + 3]);
      *(uint2*)(op + 8 * t4 + 4 * e) = a;         // d = 8t4+4e+0..3
      *(uint2*)(op + 32 + 8 * t4 + 4 * e) = b;    // d = 32+8t4+4e+0..3
    }
    if (e == 0) Lp[(ks * 16 + h) * SQ + qrow] = l;
  }
}

// ---------------- combine splits (bf16 numerators, 4 d per thread) -----------
__global__ __launch_bounds__(256) void combine(const unsigned short* __restrict__ Op,
                                               const float* __restrict__ Lp,
                                               float* __restrict__ out) {
  int idx = blockIdx.x * 256 + threadIdx.x;     // 262144 threads
  int d4 = idx & 15, q = (idx >> 4) & 1023, h = idx >> 14;
  float num[4] = {0.f, 0.f, 0.f, 0.f};
  float den = 0.f;
#pragma unroll
  for (int s = 0; s < KSPLIT; s++) {
    int row = (s * 16 + h) * SQ + q;
    uint2 pkv = *(const uint2*)(Op + row * DD + 4 * d4);
    num[0] += __builtin_bit_cast(float, pkv.x << 16);
    num[1] += __builtin_bit_cast(float, pkv.x & 0xffff0000u);
    num[2] += __builtin_bit_cast(float, pkv.y << 16);
    num[3] += __builtin_bit_cast(float, pkv.y & 0xffff0000u);
    den += Lp[row];
  }
  float r = 1.0f / den;
  float4 ov;
  ov.x = num[0] * r; ov.y = num[1] * r; ov.z = num[2] * r; ov.w = num[3] * r;
  *(float4*)(out + q * (HH * DD) + h * DD + 4 * d4) = ov;
}

extern "C" void kernel_launch(void* const* d_in, const int* in_sizes, int n_in,
                              void* d_out, int out_size, void* d_ws, size_t ws_size,
                              hipStream_t stream) {
  const float* q  = (const float*)d_in[0];
  const float* k  = (const float*)d_in[1];
  const float* v  = (const float*)d_in[2];
  const float* ck = (const float*)d_in[3];
  const float* cv = (const float*)d_in[4];
  const float* fc = (const float*)d_in[5];
  const float* fs = (const float*)d_in[6];
  float* out = (float*)d_out;
  char* ws = (char*)d_ws;

  unsigned short* Kb = (unsigned short*)(ws + KB_OFF);
  unsigned short* Vt = (unsigned short*)(ws + VT_OFF);
  unsigned short* Qb = (unsigned short*)(ws + QB_OFF);
  unsigned short* Op = (unsigned short*)(ws + OP_OFF);
  float* Lp = (float*)(ws + LP_OFF);

  prepass<<<12288, 256, 0, stream>>>(q, k, v, ck, cv, fc, fs, Kb, Vt, Qb);
  attn<<<1024, 256, 0, stream>>>(Kb, Vt, Qb, Op, Lp);
  combine<<<1024, 256, 0, stream>>>(Op, Lp, out);
}

// Round 6
// 179.772 us; speedup vs baseline: 3.8351x; 1.5232x over previous
//
#include <hip/hip_runtime.h>

// ---------------- problem constants ----------------
#define HH 16
#define DD 64
#define SQ 1024          // queries
#define LW 8192          // attention window (keys)
#define OLDK 7168        // old (already-RoPE'd) keys in window
#define CACHE_BASE 2560  // cache row index of window position 0
#define SFRAME 9728      // START_FRAME
#define KSPLIT 8
#define KPER (LW / KSPLIT)   // 1024 keys per split
#define NSTEP (KPER / 64)    // 16 K-steps of 64 keys

// ws layout (bytes)
#define KB_OFF 0u                    // bf16 Kb[h][8192][64]    = 16 MiB
#define VT_OFF 16777216u             // bf16 Vt[h][64][8192]    = 16 MiB
#define QB_OFF 33554432u             // bf16 Qb[h][1024][64]    =  2 MiB
#define OP_OFF 35651584u             // bf16 Op[ks][h][1024][64]= 16 MiB
#define LP_OFF 69206016u             // f32  Lp[ks][h][1024]    = 512 KiB

typedef __bf16 bf16x8 __attribute__((ext_vector_type(8)));
typedef float floatx16 __attribute__((ext_vector_type(16)));
typedef unsigned uintx2 __attribute__((ext_vector_type(2)));
typedef unsigned uintx4 __attribute__((ext_vector_type(4)));

__device__ __forceinline__ unsigned short f2bf(float f) {
  unsigned u = __builtin_bit_cast(unsigned, f);
  u += 0x7fffu + ((u >> 16) & 1u);           // RNE
  return (unsigned short)(u >> 16);
}

__device__ __forceinline__ float fast_exp2(float x) {
#if __has_builtin(__builtin_amdgcn_exp2f)
  return __builtin_amdgcn_exp2f(x);
#else
  return __builtin_exp2f(x);
#endif
}

// pack two f32 -> bf16x2 (as uint). element0 = a (low 16), element1 = b.
__device__ __forceinline__ unsigned pack_bf2(float a, float b) {
#if __has_builtin(__builtin_amdgcn_cvt_pk_bf16_f32)
  typedef __bf16 bf16x2_t __attribute__((ext_vector_type(2)));
  bf16x2_t r = __builtin_amdgcn_cvt_pk_bf16_f32(a, b);
  return __builtin_bit_cast(unsigned, r);
#else
  unsigned ua = __builtin_bit_cast(unsigned, a) + 0x8000u;  // round-half-up
  unsigned ub = __builtin_bit_cast(unsigned, b) + 0x8000u;
  return __builtin_amdgcn_perm(ub, ua, 0x07060302);         // [ua.hi16 | ub.hi16]
#endif
}

__device__ __forceinline__ void async16(void* lds, const void* g) {
  __builtin_amdgcn_global_load_lds((__attribute__((address_space(1))) void*)(g),
                                   (__attribute__((address_space(3))) void*)(lds),
                                   16, 0, 0);
}

// ---------------- prepass: build bf16 Kb / Vt(transposed) / Qb(rope*scale) ----
__global__ __launch_bounds__(256) void prepass(
    const float* __restrict__ qin, const float* __restrict__ kin,
    const float* __restrict__ vin, const float* __restrict__ ck,
    const float* __restrict__ cv, const float* __restrict__ fc,
    const float* __restrict__ fs, unsigned short* __restrict__ Kb,
    unsigned short* __restrict__ Vt, unsigned short* __restrict__ Qb) {
  int b = blockIdx.x, t = threadIdx.x;
  if (b < 1024) {
    // V transpose: 128kk x 64d fp32 tile (XOR col-group swizzle) -> Vt[h][d][kk]
    __shared__ float tl[128 * 64];  // row kk; float4 group c stored at cg = c ^ (kk>>3)
    int h = b >> 6, kk0 = (b & 63) * 128;
    int c = t & 15;
#pragma unroll
    for (int it = 0; it < 8; it++) {
      int kk = it * 16 + (t >> 4);
      int gk = kk0 + kk;
      const float* src = (gk < OLDK)
                             ? cv + (CACHE_BASE + gk) * (HH * DD) + h * DD + 4 * c
                             : vin + (gk - OLDK) * (HH * DD) + h * DD + 4 * c;
      float4 vv = *(const float4*)src;
      int cg = c ^ (kk >> 3);
      *(float4*)(tl + kk * 64 + cg * 4) = vv;
    }
    __syncthreads();
    int kq = t & 15;
#pragma unroll
    for (int jt = 0; jt < 4; jt++) {
      int d = jt * 16 + (t >> 4);
      ushort4 lo, hi;
      unsigned short tmp[8];
#pragma unroll
      for (int j = 0; j < 8; j++) {
        int kk = 8 * kq + j;
        int cg = (d >> 2) ^ kq;
        tmp[j] = f2bf(tl[kk * 64 + cg * 4 + (d & 3)]);
      }
      lo.x = tmp[0]; lo.y = tmp[1]; lo.z = tmp[2]; lo.w = tmp[3];
      hi.x = tmp[4]; hi.y = tmp[5]; hi.z = tmp[6]; hi.w = tmp[7];
      unsigned short* dst = Vt + (h * DD + d) * LW + kk0 + 8 * kq;
      *(ushort4*)(dst) = lo;
      *(ushort4*)(dst + 4) = hi;
    }
  } else if (b < 8192) {
    // K copy (old keys, already RoPE'd in cache): [kk][h][d] -> Kb[h][kk][d]
    int b1 = b - 1024;
    int h = b1 / 448, g = b1 % 448;
    int kk = g * 16 + (t >> 4);
    int lane = t & 15;
    float4 val = *(const float4*)(ck + (CACHE_BASE + kk) * (HH * DD) + h * DD + lane * 4);
    ushort4 o;
    o.x = f2bf(val.x); o.y = f2bf(val.y); o.z = f2bf(val.z); o.w = f2bf(val.w);
    *(ushort4*)(Kb + (h * LW + kk) * DD + lane * 4) = o;
  } else if (b < 10240) {
    // K rope (new keys)
    int b2 = b - 8192;
    int rh = b2 * 8 + (t >> 5);
    int s = rh >> 4, h = rh & 15, i = t & 31;
    float2 x = *(const float2*)(kin + s * (HH * DD) + h * DD + 2 * i);
    float c = fc[(SFRAME + s) * DD + 2 * i];
    float sn = fs[(SFRAME + s) * DD + 2 * i];
    ushort2 o;
    o.x = f2bf(x.x * c - x.y * sn);
    o.y = f2bf(x.y * c + x.x * sn);
    *(ushort2*)(Kb + (h * LW + OLDK + s) * DD + 2 * i) = o;
  } else {
    // Q rope + fold (1/sqrt(D)) * log2(e) so scores feed exp2 directly
    int b3 = b - 10240;
    int rh = b3 * 8 + (t >> 5);
    int s = rh >> 4, h = rh & 15, i = t & 31;
    const float SC = 0.18033688011112042f;  // 0.125 * log2(e)
    float2 x = *(const float2*)(qin + s * (HH * DD) + h * DD + 2 * i);
    float c = fc[(SFRAME + s) * DD + 2 * i];
    float sn = fs[(SFRAME + s) * DD + 2 * i];
    ushort2 o;
    o.x = f2bf((x.x * c - x.y * sn) * SC);
    o.y = f2bf((x.y * c + x.x * sn) * SC);
    *(ushort2*)(Qb + (h * SQ + s) * DD + 2 * i) = o;
  }
}

// ---------------- flash attention (no-max exp2 softmax, K-split 8) -----------
// 2 blocks/CU (proven no-spill). Step is software-pipelined WITHIN the wave:
//   QK(tk0) ; QK(tk1) || exp2/pack/swap(tk0) ; PV(kc01) || exp2/pack/swap(tk1)
//   ; PV(kc23)
// so VALU phases overlap the wave's own in-flight MFMAs.
__global__ __launch_bounds__(256, 2) void attn(
    const unsigned short* __restrict__ Kb, const unsigned short* __restrict__ Vt,
    const unsigned short* __restrict__ Qb, unsigned short* __restrict__ Op,
    float* __restrict__ Lp) {
  __shared__ __align__(16) unsigned char sK[2][8192];  // 64kk x 64d bf16, swizzled granules
  __shared__ __align__(16) unsigned char sV[2][8192];  // 64d x 64kk bf16, swizzled granules

  int bid = blockIdx.x;
  int g = bid & 127, qb = bid >> 7;
  int h = g & 15, ks = g >> 4;
  int t = threadIdx.x;
  int w = t >> 6, lane = t & 63;
  int l31 = lane & 31, e = lane >> 5;
  int q0 = qb * 256 + w * 64;

  // granule-position bases for the XOR swizzle (rows l31 and l31+32)
  int baseA = (l31 & 7) ^ ((l31 >> 3) & 7);
  int baseB = (l31 & 7) ^ (((l31 >> 3) + 4) & 7);

  // hoisted Q B-fragments, 2 q-tiles x 4 d-slices: B[k=d][n=q], n=l31, k=16c+8e+j
  bf16x8 qf[2][4];
#pragma unroll
  for (int tq = 0; tq < 2; tq++) {
    const unsigned short* qptr = Qb + (h * SQ + q0 + 32 * tq + l31) * DD + 8 * e;
#pragma unroll
    for (int c = 0; c < 4; c++) qf[tq][c] = *(const bf16x8*)(qptr + 16 * c);
  }

  floatx16 o[2][2];   // [tq][d-half], O^T[d][q]
#pragma unroll
  for (int a = 0; a < 2; a++)
#pragma unroll
    for (int bb = 0; bb < 2; bb++)
#pragma unroll
      for (int i = 0; i < 16; i++) o[a][bb][i] = 0.f;
  float ls[2] = {0.f, 0.f};

  const unsigned short* KbH = Kb + h * (LW * DD);
  const unsigned short* VtH = Vt + h * (DD * LW);
  int kkBase = ks * KPER;

  // stage one 64kk tile into buffer `buf` (4 async16 per wave)
  auto stage = [&](int buf, int kk0) {
#pragma unroll
    for (int hf = 0; hf < 2; hf++) {
      int gi = w * 128 + hf * 64 + lane;
      int rr = gi >> 3;                                  // kk for K, d for V
      int src = (gi & 7) ^ (rr & 7) ^ ((rr >> 3) & 7);   // source granule at position gi&7
      async16(sK[buf] + gi * 16, KbH + (kk0 + rr) * DD + src * 8);
      async16(sV[buf] + gi * 16, VtH + rr * LW + kk0 + src * 8);
    }
  };

  // softmax of one 32kk half: exp2, row-sum, pack, C->B layout swap.
  // writes pf[tq][2*tk], pf[tq][2*tk+1].
  auto softmax_half = [&](floatx16& sv, int tq, int tk, bf16x8 pf[2][4]) {
#pragma unroll
    for (int i = 0; i < 16; i++) sv[i] = fast_exp2(sv[i]);
    // pairwise-tree sum (shorter dep chain than serial)
    float p0 = (sv[0] + sv[1]) + (sv[2] + sv[3]);
    float p1 = (sv[4] + sv[5]) + (sv[6] + sv[7]);
    float p2 = (sv[8] + sv[9]) + (sv[10] + sv[11]);
    float p3 = (sv[12] + sv[13]) + (sv[14] + sv[15]);
    ls[tq] += (p0 + p1) + (p2 + p3);
#pragma unroll
    for (int kcp = 0; kcp < 2; kcp++) {
      unsigned u0 = pack_bf2(sv[8 * kcp + 0], sv[8 * kcp + 1]);
      unsigned u1 = pack_bf2(sv[8 * kcp + 2], sv[8 * kcp + 3]);
      unsigned u2 = pack_bf2(sv[8 * kcp + 4], sv[8 * kcp + 5]);
      unsigned u3 = pack_bf2(sv[8 * kcp + 6], sv[8 * kcp + 7]);
      uintx2 r0 = __builtin_amdgcn_permlane32_swap(u0, u2, false, false);
      uintx2 r1 = __builtin_amdgcn_permlane32_swap(u1, u3, false, false);
      uintx4 f;
      f[0] = r0[0]; f[1] = r1[0]; f[2] = r0[1]; f[3] = r1[1];
      pf[tq][2 * tk + kcp] = __builtin_bit_cast(bf16x8, f);
    }
  };

  stage(0, kkBase);

  for (int st = 0; st < NSTEP; st++) {
    __syncthreads();                       // buf[st&1] ready; buf[(st+1)&1] free
    if (st + 1 < NSTEP) stage((st + 1) & 1, kkBase + (st + 1) * 64);
    const unsigned char* cK = sK[st & 1];
    const unsigned char* cV = sV[st & 1];

    bf16x8 pf[2][4];   // [tq][kc_global] P in B-operand layout

    // phase 1: QK tk=0 (kk rows [0,32), swizzle baseA)
    floatx16 sA0, sA1;
#pragma unroll
    for (int i = 0; i < 16; i++) { sA0[i] = 0.f; sA1[i] = 0.f; }
#pragma unroll
    for (int c = 0; c < 4; c++) {
      int p = (2 * c + e) ^ baseA;
      bf16x8 ka = *(const bf16x8*)(cK + (l31 * 8 + p) * 16);
      sA0 = __builtin_amdgcn_mfma_f32_32x32x16_bf16(ka, qf[0][c], sA0, 0, 0, 0);
      sA1 = __builtin_amdgcn_mfma_f32_32x32x16_bf16(ka, qf[1][c], sA1, 0, 0, 0);
    }

    // phase 2: QK tk=1 (kk rows [32,64), swizzle baseB)  -- matrix pipe
    floatx16 sB0, sB1;
#pragma unroll
    for (int i = 0; i < 16; i++) { sB0[i] = 0.f; sB1[i] = 0.f; }
#pragma unroll
    for (int c = 0; c < 4; c++) {
      int p = (2 * c + e) ^ baseB;
      bf16x8 kb = *(const bf16x8*)(cK + ((l31 + 32) * 8 + p) * 16);
      sB0 = __builtin_amdgcn_mfma_f32_32x32x16_bf16(kb, qf[0][c], sB0, 0, 0, 0);
      sB1 = __builtin_amdgcn_mfma_f32_32x32x16_bf16(kb, qf[1][c], sB1, 0, 0, 0);
    }

    // phase 3: softmax tk=0 (VALU -- overlaps phase-2 MFMAs)
    softmax_half(sA0, 0, 0, pf);
    softmax_half(sA1, 1, 0, pf);

    // phase 4: PV kc=0,1 (uses pf[*][0..1] only)  -- matrix pipe
#pragma unroll
    for (int kc = 0; kc < 2; kc++) {
      int pA = (2 * kc + e) ^ baseA;
      int pB = (2 * kc + e) ^ baseB;
      bf16x8 va = *(const bf16x8*)(cV + (l31 * 8 + pA) * 16);
      bf16x8 vb = *(const bf16x8*)(cV + ((l31 + 32) * 8 + pB) * 16);
      o[0][0] = __builtin_amdgcn_mfma_f32_32x32x16_bf16(va, pf[0][kc], o[0][0], 0, 0, 0);
      o[0][1] = __builtin_amdgcn_mfma_f32_32x32x16_bf16(vb, pf[0][kc], o[0][1], 0, 0, 0);
      o[1][0] = __builtin_amdgcn_mfma_f32_32x32x16_bf16(va, pf[1][kc], o[1][0], 0, 0, 0);
      o[1][1] = __builtin_amdgcn_mfma_f32_32x32x16_bf16(vb, pf[1][kc], o[1][1], 0, 0, 0);
    }

    // phase 5: softmax tk=1 (VALU -- overlaps phase-4 MFMAs)
    softmax_half(sB0, 0, 1, pf);
    softmax_half(sB1, 1, 1, pf);

    // phase 6: PV kc=2,3
#pragma unroll
    for (int kc = 2; kc < 4; kc++) {
      int pA = (2 * kc + e) ^ baseA;
      int pB = (2 * kc + e) ^ baseB;
      bf16x8 va = *(const bf16x8*)(cV + (l31 * 8 + pA) * 16);
      bf16x8 vb = *(const bf16x8*)(cV + ((l31 + 32) * 8 + pB) * 16);
      o[0][0] = __builtin_amdgcn_mfma_f32_32x32x16_bf16(va, pf[0][kc], o[0][0], 0, 0, 0);
      o[0][1] = __builtin_amdgcn_mfma_f32_32x32x16_bf16(vb, pf[0][kc], o[0][1], 0, 0, 0);
      o[1][0] = __builtin_amdgcn_mfma_f32_32x32x16_bf16(va, pf[1][kc], o[1][0], 0, 0, 0);
      o[1][1] = __builtin_amdgcn_mfma_f32_32x32x16_bf16(vb, pf[1][kc], o[1][1], 0, 0, 0);
    }
  }

  // epilogue: store split numerators (bf16) + denominators (f32)
#pragma unroll
  for (int tq = 0; tq < 2; tq++) {
    float l = ls[tq];
    l += __shfl_xor(l, 32, 64);
    int qrow = q0 + 32 * tq + l31;
    unsigned short* op = Op + (((ks * 16 + h) * SQ) + qrow) * DD;
#pragma unroll
    for (int t4 = 0; t4 < 4; t4++) {
      uint2 a, b;
      a.x = pack_bf2(o[tq][0][4 * t4 + 0], o[tq][0][4 * t4 + 1]);
      a.y = pack_bf2(o[tq][0][4 * t4 + 2], o[tq][0][4 * t4 + 3]);
      b.x = pack_bf2(o[tq][1][4 * t4 + 0], o[tq][1][4 * t4 + 1]);
      b.y = pack_bf2(o[tq][1][4 * t4 + 2], o[tq][1][4 * t4 + 3]);
      *(uint2*)(op + 8 * t4 + 4 * e) = a;         // d = 8t4+4e+0..3
      *(uint2*)(op + 32 + 8 * t4 + 4 * e) = b;    // d = 32+8t4+4e+0..3
    }
    if (e == 0) Lp[(ks * 16 + h) * SQ + qrow] = l;
  }
}

// ---------------- combine splits (bf16 numerators, 4 d per thread) -----------
__global__ __launch_bounds__(256) void combine(const unsigned short* __restrict__ Op,
                                               const float* __restrict__ Lp,
                                               float* __restrict__ out) {
  int idx = blockIdx.x * 256 + threadIdx.x;     // 262144 threads
  int d4 = idx & 15, q = (idx >> 4) & 1023, h = idx >> 14;
  float num[4] = {0.f, 0.f, 0.f, 0.f};
  float den = 0.f;
#pragma unroll
  for (int s = 0; s < KSPLIT; s++) {
    int row = (s * 16 + h) * SQ + q;
    uint2 pkv = *(const uint2*)(Op + row * DD + 4 * d4);
    num[0] += __builtin_bit_cast(float, pkv.x << 16);
    num[1] += __builtin_bit_cast(float, pkv.x & 0xffff0000u);
    num[2] += __builtin_bit_cast(float, pkv.y << 16);
    num[3] += __builtin_bit_cast(float, pkv.y & 0xffff0000u);
    den += Lp[row];
  }
  float r = 1.0f / den;
  float4 ov;
  ov.x = num[0] * r; ov.y = num[1] * r; ov.z = num[2] * r; ov.w = num[3] * r;
  *(float4*)(out + q * (HH * DD) + h * DD + 4 * d4) = ov;
}

extern "C" void kernel_launch(void* const* d_in, const int* in_sizes, int n_in,
                              void* d_out, int out_size, void* d_ws, size_t ws_size,
                              hipStream_t stream) {
  const float* q  = (const float*)d_in[0];
  const float* k  = (const float*)d_in[1];
  const float* v  = (const float*)d_in[2];
  const float* ck = (const float*)d_in[3];
  const float* cv = (const float*)d_in[4];
  const float* fc = (const float*)d_in[5];
  const float* fs = (const float*)d_in[6];
  float* out = (float*)d_out;
  char* ws = (char*)d_ws;

  unsigned short* Kb = (unsigned short*)(ws + KB_OFF);
  unsigned short* Vt = (unsigned short*)(ws + VT_OFF);
  unsigned short* Qb = (unsigned short*)(ws + QB_OFF);
  unsigned short* Op = (unsigned short*)(ws + OP_OFF);
  float* Lp = (float*)(ws + LP_OFF);

  prepass<<<12288, 256, 0, stream>>>(q, k, v, ck, cv, fc, fs, Kb, Vt, Qb);
  attn<<<512, 256, 0, stream>>>(Kb, Vt, Qb, Op, Lp);
  combine<<<1024, 256, 0, stream>>>(Op, Lp, out);
}

// Round 7
// 177.882 us; speedup vs baseline: 3.8758x; 1.0106x over previous
//
#include <hip/hip_runtime.h>

// ---------------- problem constants ----------------
#define HH 16
#define DD 64
#define SQ 1024          // queries
#define LW 8192          // attention window (keys)
#define OLDK 7168        // old (already-RoPE'd) keys in window
#define CACHE_BASE 2560  // cache row index of window position 0
#define SFRAME 9728      // START_FRAME
#define KSPLIT 8
#define KPER (LW / KSPLIT)   // 1024 keys per split
#define NSTEP (KPER / 64)    // 16 K-steps of 64 keys

// ws layout (bytes)
#define KB_OFF 0u                    // bf16 Kb[h][8192][64]    = 16 MiB
#define VT_OFF 16777216u             // bf16 Vt[h][64][8192]    = 16 MiB
#define QB_OFF 33554432u             // bf16 Qb[h][1024][64]    =  2 MiB
#define OP_OFF 35651584u             // bf16 Op[ks][h][1024][64]= 16 MiB
#define LP_OFF 69206016u             // f32  Lp[ks][h][1024]    = 512 KiB

typedef __bf16 bf16x8 __attribute__((ext_vector_type(8)));
typedef float floatx16 __attribute__((ext_vector_type(16)));
typedef float floatx2 __attribute__((ext_vector_type(2)));
typedef unsigned uintx2 __attribute__((ext_vector_type(2)));
typedef unsigned uintx4 __attribute__((ext_vector_type(4)));

__device__ __forceinline__ unsigned short f2bf(float f) {
  unsigned u = __builtin_bit_cast(unsigned, f);
  u += 0x7fffu + ((u >> 16) & 1u);           // RNE
  return (unsigned short)(u >> 16);
}

__device__ __forceinline__ float fast_exp2(float x) {
#if __has_builtin(__builtin_amdgcn_exp2f)
  return __builtin_amdgcn_exp2f(x);
#else
  return __builtin_exp2f(x);
#endif
}

// pack two f32 -> bf16x2 (as uint). element0 = a (low 16), element1 = b.
__device__ __forceinline__ unsigned pack_bf2(float a, float b) {
#if __has_builtin(__builtin_amdgcn_cvt_pk_bf16_f32)
  typedef __bf16 bf16x2_t __attribute__((ext_vector_type(2)));
  bf16x2_t r = __builtin_amdgcn_cvt_pk_bf16_f32(a, b);
  return __builtin_bit_cast(unsigned, r);
#else
  unsigned ua = __builtin_bit_cast(unsigned, a) + 0x8000u;  // round-half-up
  unsigned ub = __builtin_bit_cast(unsigned, b) + 0x8000u;
  return __builtin_amdgcn_perm(ub, ua, 0x07060302);         // [ua.hi16 | ub.hi16]
#endif
}

__device__ __forceinline__ void async16(void* lds, const void* g) {
  __builtin_amdgcn_global_load_lds((__attribute__((address_space(1))) void*)(g),
                                   (__attribute__((address_space(3))) void*)(lds),
                                   16, 0, 0);
}

// ---------------- prepass: build bf16 Kb / Vt(transposed) / Qb(rope*scale) ----
__global__ __launch_bounds__(256) void prepass(
    const float* __restrict__ qin, const float* __restrict__ kin,
    const float* __restrict__ vin, const float* __restrict__ ck,
    const float* __restrict__ cv, const float* __restrict__ fc,
    const float* __restrict__ fs, unsigned short* __restrict__ Kb,
    unsigned short* __restrict__ Vt, unsigned short* __restrict__ Qb) {
  int b = blockIdx.x, t = threadIdx.x;
  if (b < 1024) {
    // V transpose: 128kk x 64d fp32 tile -> Vt[h][d][kk]
    // rows padded to 65 floats: transpose-read lane stride = 8*65 = 520 words
    // == 8 mod 32 banks -> 4-way conflict (was 16-way at stride 64)
    __shared__ float tl[128 * 65];
    int h = b >> 6, kk0 = (b & 63) * 128;
    int c = t & 15;
#pragma unroll
    for (int it = 0; it < 8; it++) {
      int kk = it * 16 + (t >> 4);
      int gk = kk0 + kk;
      const float* src = (gk < OLDK)
                             ? cv + (CACHE_BASE + gk) * (HH * DD) + h * DD + 4 * c
                             : vin + (gk - OLDK) * (HH * DD) + h * DD + 4 * c;
      float4 vv = *(const float4*)src;
      *(float4*)(tl + kk * 65 + c * 4) = vv;
    }
    __syncthreads();
    int kq = t & 15;
#pragma unroll
    for (int jt = 0; jt < 4; jt++) {
      int d = jt * 16 + (t >> 4);
      ushort4 lo, hi;
      unsigned short tmp[8];
#pragma unroll
      for (int j = 0; j < 8; j++) {
        int kk = 8 * kq + j;
        tmp[j] = f2bf(tl[kk * 65 + d]);
      }
      lo.x = tmp[0]; lo.y = tmp[1]; lo.z = tmp[2]; lo.w = tmp[3];
      hi.x = tmp[4]; hi.y = tmp[5]; hi.z = tmp[6]; hi.w = tmp[7];
      unsigned short* dst = Vt + (h * DD + d) * LW + kk0 + 8 * kq;
      *(ushort4*)(dst) = lo;
      *(ushort4*)(dst + 4) = hi;
    }
  } else if (b < 8192) {
    // K copy (old keys, already RoPE'd in cache): [kk][h][d] -> Kb[h][kk][d]
    int b1 = b - 1024;
    int h = b1 / 448, g = b1 % 448;
    int kk = g * 16 + (t >> 4);
    int lane = t & 15;
    float4 val = *(const float4*)(ck + (CACHE_BASE + kk) * (HH * DD) + h * DD + lane * 4);
    ushort4 o;
    o.x = f2bf(val.x); o.y = f2bf(val.y); o.z = f2bf(val.z); o.w = f2bf(val.w);
    *(ushort4*)(Kb + (h * LW + kk) * DD + lane * 4) = o;
  } else if (b < 10240) {
    // K rope (new keys)
    int b2 = b - 8192;
    int rh = b2 * 8 + (t >> 5);
    int s = rh >> 4, h = rh & 15, i = t & 31;
    float2 x = *(const float2*)(kin + s * (HH * DD) + h * DD + 2 * i);
    float c = fc[(SFRAME + s) * DD + 2 * i];
    float sn = fs[(SFRAME + s) * DD + 2 * i];
    ushort2 o;
    o.x = f2bf(x.x * c - x.y * sn);
    o.y = f2bf(x.y * c + x.x * sn);
    *(ushort2*)(Kb + (h * LW + OLDK + s) * DD + 2 * i) = o;
  } else {
    // Q rope + fold (1/sqrt(D)) * log2(e) so scores feed exp2 directly
    int b3 = b - 10240;
    int rh = b3 * 8 + (t >> 5);
    int s = rh >> 4, h = rh & 15, i = t & 31;
    const float SC = 0.18033688011112042f;  // 0.125 * log2(e)
    float2 x = *(const float2*)(qin + s * (HH * DD) + h * DD + 2 * i);
    float c = fc[(SFRAME + s) * DD + 2 * i];
    float sn = fs[(SFRAME + s) * DD + 2 * i];
    ushort2 o;
    o.x = f2bf((x.x * c - x.y * sn) * SC);
    o.y = f2bf((x.y * c + x.x * sn) * SC);
    *(ushort2*)(Qb + (h * SQ + s) * DD + 2 * i) = o;
  }
}

// ---------------- flash attention (no-max exp2 softmax, K-split 8) -----------
// 2 blocks/CU (proven no-spill). Within-wave 6-phase pipeline; this revision
// trims VALU: hoisted zero-C for QK chains (no per-step acc re-zeroing),
// packed float2 row-sums (v_pk_add_f32), prefetch issued after QK(tk0) so the
// barrier->first-MFMA head is not blocked by staging address math.
__global__ __launch_bounds__(256, 2) void attn(
    const unsigned short* __restrict__ Kb, const unsigned short* __restrict__ Vt,
    const unsigned short* __restrict__ Qb, unsigned short* __restrict__ Op,
    float* __restrict__ Lp) {
  __shared__ __align__(16) unsigned char sK[2][8192];  // 64kk x 64d bf16, swizzled granules
  __shared__ __align__(16) unsigned char sV[2][8192];  // 64d x 64kk bf16, swizzled granules

  int bid = blockIdx.x;
  int g = bid & 127, qb = bid >> 7;
  int h = g & 15, ks = g >> 4;
  int t = threadIdx.x;
  int w = t >> 6, lane = t & 63;
  int l31 = lane & 31, e = lane >> 5;
  int q0 = qb * 256 + w * 64;

  // granule-position bases for the XOR swizzle (rows l31 and l31+32)
  int baseA = (l31 & 7) ^ ((l31 >> 3) & 7);
  int baseB = (l31 & 7) ^ (((l31 >> 3) + 4) & 7);

  // hoisted Q B-fragments, 2 q-tiles x 4 d-slices: B[k=d][n=q], n=l31, k=16c+8e+j
  bf16x8 qf[2][4];
#pragma unroll
  for (int tq = 0; tq < 2; tq++) {
    const unsigned short* qptr = Qb + (h * SQ + q0 + 32 * tq + l31) * DD + 8 * e;
#pragma unroll
    for (int c = 0; c < 4; c++) qf[tq][c] = *(const bf16x8*)(qptr + 16 * c);
  }

  floatx16 o[2][2];   // [tq][d-half], O^T[d][q]
#pragma unroll
  for (int a = 0; a < 2; a++)
#pragma unroll
    for (int bb = 0; bb < 2; bb++)
#pragma unroll
      for (int i = 0; i < 16; i++) o[a][bb][i] = 0.f;
  float ls[2] = {0.f, 0.f};

  const floatx16 fz = {0.f};   // hoisted zero C-operand for QK chains

  const unsigned short* KbH = Kb + h * (LW * DD);
  const unsigned short* VtH = Vt + h * (DD * LW);
  int kkBase = ks * KPER;

  // stage one 64kk tile into buffer `buf` (4 async16 per wave)
  auto stage = [&](int buf, int kk0) {
#pragma unroll
    for (int hf = 0; hf < 2; hf++) {
      int gi = w * 128 + hf * 64 + lane;
      int rr = gi >> 3;                                  // kk for K, d for V
      int src = (gi & 7) ^ (rr & 7) ^ ((rr >> 3) & 7);   // source granule at position gi&7
      async16(sK[buf] + gi * 16, KbH + (kk0 + rr) * DD + src * 8);
      async16(sV[buf] + gi * 16, VtH + rr * LW + kk0 + src * 8);
    }
  };

  // softmax of one 32kk half: exp2, packed row-sum, pack, C->B layout swap.
  auto softmax_half = [&](floatx16& sv, int tq, int tk, bf16x8 pf[2][4]) {
#pragma unroll
    for (int i = 0; i < 16; i++) sv[i] = fast_exp2(sv[i]);
    // packed pairwise tree sum -> v_pk_add_f32
    floatx2 t0, t1, t2, t3;
    t0[0] = sv[0];  t0[1] = sv[1];
    t1[0] = sv[2];  t1[1] = sv[3];
    t2[0] = sv[4];  t2[1] = sv[5];
    t3[0] = sv[6];  t3[1] = sv[7];
    floatx2 u0 = t0 + t1, u1 = t2 + t3;
    floatx2 t4, t5, t6, t7;
    t4[0] = sv[8];  t4[1] = sv[9];
    t5[0] = sv[10]; t5[1] = sv[11];
    t6[0] = sv[12]; t6[1] = sv[13];
    t7[0] = sv[14]; t7[1] = sv[15];
    floatx2 u2 = t4 + t5, u3 = t6 + t7;
    floatx2 v0 = u0 + u1, v1 = u2 + u3;
    floatx2 vs = v0 + v1;
    ls[tq] += vs[0] + vs[1];
#pragma unroll
    for (int kcp = 0; kcp < 2; kcp++) {
      unsigned u0p = pack_bf2(sv[8 * kcp + 0], sv[8 * kcp + 1]);
      unsigned u1p = pack_bf2(sv[8 * kcp + 2], sv[8 * kcp + 3]);
      unsigned u2p = pack_bf2(sv[8 * kcp + 4], sv[8 * kcp + 5]);
      unsigned u3p = pack_bf2(sv[8 * kcp + 6], sv[8 * kcp + 7]);
      uintx2 r0 = __builtin_amdgcn_permlane32_swap(u0p, u2p, false, false);
      uintx2 r1 = __builtin_amdgcn_permlane32_swap(u1p, u3p, false, false);
      uintx4 f;
      f[0] = r0[0]; f[1] = r1[0]; f[2] = r0[1]; f[3] = r1[1];
      pf[tq][2 * tk + kcp] = __builtin_bit_cast(bf16x8, f);
    }
  };

  stage(0, kkBase);

  for (int st = 0; st < NSTEP; st++) {
    __syncthreads();                       // buf[st&1] ready; buf[(st+1)&1] free
    const unsigned char* cK = sK[st & 1];
    const unsigned char* cV = sV[st & 1];

    bf16x8 pf[2][4];   // [tq][kc_global] P in B-operand layout

    // phase 1: QK tk=0 (kk rows [0,32), swizzle baseA); c=0 peeled with zero C
    floatx16 sA0, sA1;
    {
      int p0 = e ^ baseA;
      bf16x8 ka0 = *(const bf16x8*)(cK + (l31 * 8 + p0) * 16);
      sA0 = __builtin_amdgcn_mfma_f32_32x32x16_bf16(ka0, qf[0][0], fz, 0, 0, 0);
      sA1 = __builtin_amdgcn_mfma_f32_32x32x16_bf16(ka0, qf[1][0], fz, 0, 0, 0);
#pragma unroll
      for (int c = 1; c < 4; c++) {
        int p = (2 * c + e) ^ baseA;
        bf16x8 ka = *(const bf16x8*)(cK + (l31 * 8 + p) * 16);
        sA0 = __builtin_amdgcn_mfma_f32_32x32x16_bf16(ka, qf[0][c], sA0, 0, 0, 0);
        sA1 = __builtin_amdgcn_mfma_f32_32x32x16_bf16(ka, qf[1][c], sA1, 0, 0, 0);
      }
    }

    // prefetch next tile now: addressing VALU overlaps phase-1 MFMAs already
    // in flight, and loads get the remaining ~3/4 of the step to land.
    if (st + 1 < NSTEP) stage((st + 1) & 1, kkBase + (st + 1) * 64);

    // phase 2: QK tk=1 (kk rows [32,64), swizzle baseB)  -- matrix pipe
    floatx16 sB0, sB1;
    {
      int p0 = e ^ baseB;
      bf16x8 kb0 = *(const bf16x8*)(cK + ((l31 + 32) * 8 + p0) * 16);
      sB0 = __builtin_amdgcn_mfma_f32_32x32x16_bf16(kb0, qf[0][0], fz, 0, 0, 0);
      sB1 = __builtin_amdgcn_mfma_f32_32x32x16_bf16(kb0, qf[1][0], fz, 0, 0, 0);
#pragma unroll
      for (int c = 1; c < 4; c++) {
        int p = (2 * c + e) ^ baseB;
        bf16x8 kb = *(const bf16x8*)(cK + ((l31 + 32) * 8 + p) * 16);
        sB0 = __builtin_amdgcn_mfma_f32_32x32x16_bf16(kb, qf[0][c], sB0, 0, 0, 0);
        sB1 = __builtin_amdgcn_mfma_f32_32x32x16_bf16(kb, qf[1][c], sB1, 0, 0, 0);
      }
    }

    // phase 3: softmax tk=0 (VALU -- overlaps phase-2 MFMAs)
    softmax_half(sA0, 0, 0, pf);
    softmax_half(sA1, 1, 0, pf);

    // phase 4: PV kc=0,1 (uses pf[*][0..1] only)  -- matrix pipe
#pragma unroll
    for (int kc = 0; kc < 2; kc++) {
      int pA = (2 * kc + e) ^ baseA;
      int pB = (2 * kc + e) ^ baseB;
      bf16x8 va = *(const bf16x8*)(cV + (l31 * 8 + pA) * 16);
      bf16x8 vb = *(const bf16x8*)(cV + ((l31 + 32) * 8 + pB) * 16);
      o[0][0] = __builtin_amdgcn_mfma_f32_32x32x16_bf16(va, pf[0][kc], o[0][0], 0, 0, 0);
      o[0][1] = __builtin_amdgcn_mfma_f32_32x32x16_bf16(vb, pf[0][kc], o[0][1], 0, 0, 0);
      o[1][0] = __builtin_amdgcn_mfma_f32_32x32x16_bf16(va, pf[1][kc], o[1][0], 0, 0, 0);
      o[1][1] = __builtin_amdgcn_mfma_f32_32x32x16_bf16(vb, pf[1][kc], o[1][1], 0, 0, 0);
    }

    // phase 5: softmax tk=1 (VALU -- overlaps phase-4 MFMAs)
    softmax_half(sB0, 0, 1, pf);
    softmax_half(sB1, 1, 1, pf);

    // phase 6: PV kc=2,3
#pragma unroll
    for (int kc = 2; kc < 4; kc++) {
      int pA = (2 * kc + e) ^ baseA;
      int pB = (2 * kc + e) ^ baseB;
      bf16x8 va = *(const bf16x8*)(cV + (l31 * 8 + pA) * 16);
      bf16x8 vb = *(const bf16x8*)(cV + ((l31 + 32) * 8 + pB) * 16);
      o[0][0] = __builtin_amdgcn_mfma_f32_32x32x16_bf16(va, pf[0][kc], o[0][0], 0, 0, 0);
      o[0][1] = __builtin_amdgcn_mfma_f32_32x32x16_bf16(vb, pf[0][kc], o[0][1], 0, 0, 0);
      o[1][0] = __builtin_amdgcn_mfma_f32_32x32x16_bf16(va, pf[1][kc], o[1][0], 0, 0, 0);
      o[1][1] = __builtin_amdgcn_mfma_f32_32x32x16_bf16(vb, pf[1][kc], o[1][1], 0, 0, 0);
    }
  }

  // epilogue: store split numerators (bf16) + denominators (f32)
#pragma unroll
  for (int tq = 0; tq < 2; tq++) {
    float l = ls[tq];
    l += __shfl_xor(l, 32, 64);
    int qrow = q0 + 32 * tq + l31;
    unsigned short* op = Op + (((ks * 16 + h) * SQ) + qrow) * DD;
#pragma unroll
    for (int t4 = 0; t4 < 4; t4++) {
      uint2 a, b;
      a.x = pack_bf2(o[tq][0][4 * t4 + 0], o[tq][0][4 * t4 + 1]);
      a.y = pack_bf2(o[tq][0][4 * t4 + 2], o[tq][0][4 * t4 + 3]);
      b.x = pack_bf2(o[tq][1][4 * t4 + 0], o[tq][1][4 * t4 + 1]);
      b.y = pack_bf2(o[tq][1][4 * t4 + 2], o[tq][1][4 * t4 + 3]);
      *(uint2*)(op + 8 * t4 + 4 * e) = a;         // d = 8t4+4e+0..3
      *(uint2*)(op + 32 + 8 * t4 + 4 * e) = b;    // d = 32+8t4+4e+0..3
    }
    if (e == 0) Lp[(ks * 16 + h) * SQ + qrow] = l;
  }
}

// ---------------- combine splits (bf16 numerators, 4 d per thread) -----------
__global__ __launch_bounds__(256) void combine(const unsigned short* __restrict__ Op,
                                               const float* __restrict__ Lp,
                                               float* __restrict__ out) {
  int idx = blockIdx.x * 256 + threadIdx.x;     // 262144 threads
  int d4 = idx & 15, q = (idx >> 4) & 1023, h = idx >> 14;
  float num[4] = {0.f, 0.f, 0.f, 0.f};
  float den = 0.f;
#pragma unroll
  for (int s = 0; s < KSPLIT; s++) {
    int row = (s * 16 + h) * SQ + q;
    uint2 pkv = *(const uint2*)(Op + row * DD + 4 * d4);
    num[0] += __builtin_bit_cast(float, pkv.x << 16);
    num[1] += __builtin_bit_cast(float, pkv.x & 0xffff0000u);
    num[2] += __builtin_bit_cast(float, pkv.y << 16);
    num[3] += __builtin_bit_cast(float, pkv.y & 0xffff0000u);
    den += Lp[row];
  }
  float r = 1.0f / den;
  float4 ov;
  ov.x = num[0] * r; ov.y = num[1] * r; ov.z = num[2] * r; ov.w = num[3] * r;
  *(float4*)(out + q * (HH * DD) + h * DD + 4 * d4) = ov;
}

extern "C" void kernel_launch(void* const* d_in, const int* in_sizes, int n_in,
                              void* d_out, int out_size, void* d_ws, size_t ws_size,
                              hipStream_t stream) {
  const float* q  = (const float*)d_in[0];
  const float* k  = (const float*)d_in[1];
  const float* v  = (const float*)d_in[2];
  const float* ck = (const float*)d_in[3];
  const float* cv = (const float*)d_in[4];
  const float* fc = (const float*)d_in[5];
  const float* fs = (const float*)d_in[6];
  float* out = (float*)d_out;
  char* ws = (char*)d_ws;

  unsigned short* Kb = (unsigned short*)(ws + KB_OFF);
  unsigned short* Vt = (unsigned short*)(ws + VT_OFF);
  unsigned short* Qb = (unsigned short*)(ws + QB_OFF);
  unsigned short* Op = (unsigned short*)(ws + OP_OFF);
  float* Lp = (float*)(ws + LP_OFF);

  prepass<<<12288, 256, 0, stream>>>(q, k, v, ck, cv, fc, fs, Kb, Vt, Qb);
  attn<<<512, 256, 0, stream>>>(Kb, Vt, Qb, Op, Lp);
  combine<<<1024, 256, 0, stream>>>(Op, Lp, out);
}